// Round 1
// baseline (799.334 us; speedup 1.0000x reference)
//
#include <hip/hip_runtime.h>

#define TT 2048      // tokens (B*S)
#define HD 2048      // hidden
#define FD 1408      // per-expert ffn
#define SFD 5632     // shared ffn
#define NE 8         // experts
#define BM 128
#define BN 128
#define BK 32

using f32x4 = __attribute__((ext_vector_type(4))) float;
using s16x8 = __attribute__((ext_vector_type(8))) short;

__device__ __forceinline__ unsigned short f2bf(float f) {
    union { float f; unsigned u; } v; v.f = f;
    unsigned r = v.u + 0x7fff + ((v.u >> 16) & 1);   // RNE
    return (unsigned short)(r >> 16);
}
__device__ __forceinline__ float bf2f(unsigned short u) {
    union { unsigned u; float f; } v; v.u = ((unsigned)u) << 16;
    return v.f;
}

// ---- fp32 -> bf16 activation conversion -------------------------------------
__global__ void cvt_kernel(const float* __restrict__ x, unsigned short* __restrict__ xb) {
    size_t i = ((size_t)blockIdx.x * 256 + threadIdx.x) * 8;
    float4 f0 = *(const float4*)(x + i);
    float4 f1 = *(const float4*)(x + i + 4);
    s16x8 v;
    v[0]=(short)f2bf(f0.x); v[1]=(short)f2bf(f0.y); v[2]=(short)f2bf(f0.z); v[3]=(short)f2bf(f0.w);
    v[4]=(short)f2bf(f1.x); v[5]=(short)f2bf(f1.y); v[6]=(short)f2bf(f1.z); v[7]=(short)f2bf(f1.w);
    *(s16x8*)(xb + i) = v;
}

// ---- router: fp32 softmax, top-2, expert lists, shared sigmoid gate ---------
__global__ void router_kernel(const float* __restrict__ x, const float* __restrict__ gw,
                              const float* __restrict__ segw,
                              int* counts, int* tlist, float* wlist, float* gateval) {
    int wave = threadIdx.x >> 6;
    int lane = threadIdx.x & 63;
    int t = blockIdx.x * 4 + wave;
    float acc[9];
    #pragma unroll
    for (int i = 0; i < 9; ++i) acc[i] = 0.f;
    const float* xrow = x + (size_t)t * HD;
    for (int h = lane; h < HD; h += 64) {
        float xv = xrow[h];
        #pragma unroll
        for (int e = 0; e < NE; ++e) acc[e] += xv * gw[e * HD + h];
        acc[8] += xv * segw[h];
    }
    #pragma unroll
    for (int i = 0; i < 9; ++i) {
        float v = acc[i];
        #pragma unroll
        for (int s = 32; s > 0; s >>= 1) v += __shfl_xor(v, s);
        acc[i] = v;
    }
    if (lane == 0) {
        float m = acc[0];
        #pragma unroll
        for (int e = 1; e < NE; ++e) m = fmaxf(m, acc[e]);
        float p[NE], sum = 0.f;
        #pragma unroll
        for (int e = 0; e < NE; ++e) { p[e] = expf(acc[e] - m); sum += p[e]; }
        float inv = 1.f / sum;
        int b1 = 0, b2 = -1; float v1 = p[0], v2 = -1.f;
        #pragma unroll
        for (int e = 1; e < NE; ++e) {
            if (p[e] > v1) { v2 = v1; b2 = b1; v1 = p[e]; b1 = e; }
            else if (p[e] > v2) { v2 = p[e]; b2 = e; }
        }
        v1 *= inv; v2 *= inv;
        int s1 = atomicAdd(&counts[b1], 1); tlist[b1 * TT + s1] = t; wlist[b1 * TT + s1] = v1;
        int s2 = atomicAdd(&counts[b2], 1); tlist[b2 * TT + s2] = t; wlist[b2 * TT + s2] = v2;
        gateval[t] = 1.f / (1.f + expf(-acc[8]));
    }
}

__global__ void prefix_kernel(const int* counts, int* offsets) {
    if (threadIdx.x == 0) {
        int s = 0;
        for (int e = 0; e < NE; ++e) { offsets[e] = s; s += counts[e]; }
    }
}

// ---- GEMM: C[M,N] = A[M,K](bf16) @ B[N,K](fp32->bf16)^T ---------------------
// EPI 0: store bf16 C        (gate proj)
// EPI 1: C = silu(C)*acc     (up proj, SwiGLU fused, in-place)
// EPI 2: atomicAdd out[token] += wlist*acc   (routed down)
// EPI 3: out[row] = gateval[row]*acc         (shared down; writes full out)
template<int EPI, bool GATHER>
__global__ __launch_bounds__(256)
void gemm_tpl(const unsigned short* __restrict__ A, int lda,
              const float* __restrict__ B, size_t eStrideB, int ldb, int K,
              int Mfixed, const int* __restrict__ counts, const int* __restrict__ offsets,
              const int* __restrict__ tlist, const float* __restrict__ wlist,
              unsigned short* __restrict__ C, int ldc,
              const float* __restrict__ gateval, float* __restrict__ out, int ldout) {
    __shared__ s16x8 Asl[512];
    __shared__ s16x8 Bsl[512];
    int e = blockIdx.z;
    int M = counts ? counts[e] : Mfixed;
    int m0 = blockIdx.y * BM;
    if (m0 >= M) return;
    int n0 = blockIdx.x * BN;
    int row_off = offsets ? offsets[e] : 0;
    int lbase = e * TT;
    const float* Bp = B + (size_t)e * eStrideB;
    int tid = threadIdx.x;

    // staging assignment: thread t handles row t>>1, k-groups {(t&1)*2, (t&1)*2+1}
    int srow = tid >> 1;
    int ar = m0 + srow; if (ar > M - 1) ar = M - 1;
    size_t arow = GATHER ? (size_t)tlist[lbase + ar] : (size_t)(row_off + ar);
    const unsigned short* Arowp = A + arow * (size_t)lda;
    const float* Browp = Bp + (size_t)(n0 + srow) * ldb;
    int kg0 = (tid & 1) * 2;

    int lane = tid & 63;
    int wv = tid >> 6;
    int wm = (wv >> 1) * 64, wn = (wv & 1) * 64;
    int grp = lane >> 4, l16 = lane & 15;

    f32x4 acc[4][4];
    f32x4 zero = {0.f, 0.f, 0.f, 0.f};
    #pragma unroll
    for (int mi = 0; mi < 4; ++mi)
        #pragma unroll
        for (int ni = 0; ni < 4; ++ni) acc[mi][ni] = zero;

    for (int k0 = 0; k0 < K; k0 += BK) {
        __syncthreads();
        #pragma unroll
        for (int j = 0; j < 2; ++j) {            // A: bf16 copy, 16B/thread/slot
            int g = kg0 + j;
            Asl[g * 128 + srow] = *(const s16x8*)(Arowp + k0 + g * 8);
        }
        #pragma unroll
        for (int j = 0; j < 2; ++j) {            // B: fp32 load + cvt
            int g = kg0 + j;
            const float* p = Browp + k0 + g * 8;
            float4 f0 = *(const float4*)p;
            float4 f1 = *(const float4*)(p + 4);
            s16x8 v;
            v[0]=(short)f2bf(f0.x); v[1]=(short)f2bf(f0.y); v[2]=(short)f2bf(f0.z); v[3]=(short)f2bf(f0.w);
            v[4]=(short)f2bf(f1.x); v[5]=(short)f2bf(f1.y); v[6]=(short)f2bf(f1.z); v[7]=(short)f2bf(f1.w);
            Bsl[g * 128 + srow] = v;
        }
        __syncthreads();
        s16x8 af[4], bfr[4];
        #pragma unroll
        for (int i = 0; i < 4; ++i) af[i]  = Asl[grp * 128 + wm + i * 16 + l16];
        #pragma unroll
        for (int i = 0; i < 4; ++i) bfr[i] = Bsl[grp * 128 + wn + i * 16 + l16];
        #pragma unroll
        for (int mi = 0; mi < 4; ++mi)
            #pragma unroll
            for (int ni = 0; ni < 4; ++ni)
                acc[mi][ni] = __builtin_amdgcn_mfma_f32_16x16x32_bf16(af[mi], bfr[ni], acc[mi][ni], 0, 0, 0);
    }

    // epilogue: D row = (lane>>4)*4 + r, col = lane&15 (per 16x16 frag)
    #pragma unroll
    for (int mi = 0; mi < 4; ++mi) {
        #pragma unroll
        for (int r = 0; r < 4; ++r) {
            int mrow = m0 + wm + mi * 16 + (lane >> 4) * 4 + r;
            if (mrow >= M) continue;
            int tok = 0; float w = 0.f;
            if (EPI == 2) { tok = tlist[lbase + mrow]; w = wlist[lbase + mrow]; }
            #pragma unroll
            for (int ni = 0; ni < 4; ++ni) {
                int col = n0 + wn + ni * 16 + l16;
                float v = acc[mi][ni][r];
                if (EPI == 0) {
                    C[(size_t)(row_off + mrow) * ldc + col] = f2bf(v);
                } else if (EPI == 1) {
                    size_t idx = (size_t)(row_off + mrow) * ldc + col;
                    float g = bf2f(C[idx]);
                    C[idx] = f2bf(g * v / (1.f + __expf(-g)));
                } else if (EPI == 2) {
                    atomicAdd(out + (size_t)tok * ldout + col, w * v);
                } else {
                    out[(size_t)mrow * ldout + col] = gateval[mrow] * v;
                }
            }
        }
    }
}

extern "C" void kernel_launch(void* const* d_in, const int* in_sizes, int n_in,
                              void* d_out, int out_size, void* d_ws, size_t ws_size,
                              hipStream_t stream) {
    const float* x    = (const float*)d_in[0];
    const float* gw   = (const float*)d_in[1];
    const float* gpw  = (const float*)d_in[2];
    const float* upw  = (const float*)d_in[3];
    const float* dpw  = (const float*)d_in[4];
    const float* sgw  = (const float*)d_in[5];
    const float* suw  = (const float*)d_in[6];
    const float* sdw  = (const float*)d_in[7];
    const float* segw = (const float*)d_in[8];
    float* out = (float*)d_out;
    char* ws = (char*)d_ws;

    int*   counts  = (int*)(ws + 0);
    int*   offsets = (int*)(ws + 64);
    int*   tlist   = (int*)(ws + 256);            // 8*2048*4 = 64KB
    float* wlist   = (float*)(ws + 65792);        // 64KB
    float* gateval = (float*)(ws + 131328);       // 8KB
    unsigned short* xb   = (unsigned short*)(ws + 139520);    // 8MB bf16 activations
    unsigned short* gbuf = (unsigned short*)(ws + 8528128);   // 23MB, time-shared shared/routed

    hipMemsetAsync(counts, 0, 64, stream);
    cvt_kernel<<<dim3(TT * HD / (256 * 8)), 256, 0, stream>>>(x, xb);
    router_kernel<<<dim3(TT / 4), 256, 0, stream>>>(x, gw, segw, counts, tlist, wlist, gateval);
    prefix_kernel<<<dim3(1), 64, 0, stream>>>(counts, offsets);

    // ---- shared expert path (writes full out, so no memset of d_out needed) ----
    gemm_tpl<0, false><<<dim3(SFD / BN, TT / BM, 1), 256, 0, stream>>>(
        xb, HD, sgw, 0, HD, HD, TT, nullptr, nullptr, nullptr, nullptr, gbuf, SFD, nullptr, nullptr, 0);
    gemm_tpl<1, false><<<dim3(SFD / BN, TT / BM, 1), 256, 0, stream>>>(
        xb, HD, suw, 0, HD, HD, TT, nullptr, nullptr, nullptr, nullptr, gbuf, SFD, nullptr, nullptr, 0);
    gemm_tpl<3, false><<<dim3(HD / BN, TT / BM, 1), 256, 0, stream>>>(
        gbuf, SFD, sdw, 0, SFD, SFD, TT, nullptr, nullptr, nullptr, nullptr, nullptr, 0, gateval, out, HD);

    // ---- routed experts (sparse top-2 dispatch), atomicAdd on top of shared ----
    gemm_tpl<0, true><<<dim3(FD / BN, TT / BM, NE), 256, 0, stream>>>(
        xb, HD, gpw, (size_t)FD * HD, HD, HD, 0, counts, offsets, tlist, wlist, gbuf, FD, nullptr, nullptr, 0);
    gemm_tpl<1, true><<<dim3(FD / BN, TT / BM, NE), 256, 0, stream>>>(
        xb, HD, upw, (size_t)FD * HD, HD, HD, 0, counts, offsets, tlist, wlist, gbuf, FD, nullptr, nullptr, 0);
    gemm_tpl<2, false><<<dim3(HD / BN, TT / BM, NE), 256, 0, stream>>>(
        gbuf, FD, dpw, (size_t)HD * FD, FD, FD, 0, counts, offsets, tlist, wlist, nullptr, 0, nullptr, out, HD);
}